// Round 13
// baseline (258.071 us; speedup 1.0000x reference)
//
#include <hip/hip_runtime.h>

#define BB 2
#define NN 16384
#define KK 4096
#define CC 128
#define SS 32
#define BKK (BB * KK)

typedef float vfloat4 __attribute__((ext_vector_type(4)));

// ---------------------------------------------------------------------------
// Kernel A: transpose features [B][C][N] -> [B][N][C] + fused xyzw prep.
// UNCHANGED (absmax 0.0 verified rounds 2/4/6/7/8/10/11/12).
// ---------------------------------------------------------------------------
__global__ __launch_bounds__(256) void transpose_prep_kernel(
    const float* __restrict__ feat, const float* __restrict__ xyz,
    float* __restrict__ feat_t, float* __restrict__ xyzw)
{
    __shared__ float tile[64][133];
    const int b  = blockIdx.x >> 8;          // NN/64 = 256 tiles per batch
    const int n0 = (blockIdx.x & 255) * 64;
    const int t  = threadIdx.x;

    if (t < 64) {
        const int i = b * NN + n0 + t;
        const float* p = xyz + (size_t)i * 3;
        const float x = p[0], y = p[1], z = p[2];
        const float pp = __fadd_rn(__fadd_rn(__fmul_rn(x, x), __fmul_rn(y, y)),
                                   __fmul_rn(z, z));
        vfloat4 v = {x, y, z, pp};
        *(vfloat4*)(xyzw + (size_t)i * 4) = v;
    }

    const int ln = t & 63;
    const int cr = t >> 6;                   // 0..3
#pragma unroll
    for (int p = 0; p < 32; ++p) {
        const int c = p * 4 + cr;
        tile[ln][c] = feat[((size_t)b * CC + c) * NN + n0 + ln];
    }
    __syncthreads();

    const int cl = t & 31;
    const int ns = t >> 5;                   // 0..7
#pragma unroll
    for (int p = 0; p < 8; ++p) {
        const int n = ns + 8 * p;
        float* dst = feat_t + ((size_t)(b * NN + n0 + n)) * CC;
#pragma unroll
        for (int j = 0; j < 4; ++j)
            dst[cl + 32 * j] = tile[n][cl + 32 * j];
    }
}

// ---------------------------------------------------------------------------
// Kernel B: ball query — MEASUREMENT PROBE. Body is the round-7 kernel
// verbatim (best config, ~42us inferred); grid.y = 6 replicas doing
// byte-identical work. Replica 0 writes idx_buf; replicas 1..5 write to
// scratch (inside d_out's feature region, overwritten by group later).
// Purpose: lift ball above the 80us fill dispatches -> read VALUBusy /
// FETCH_SIZE / Occupancy to classify issue- vs latency- vs BW-bound.
// REVERT replication next round. Float exprs EXACT -> absmax 0.0.
// ---------------------------------------------------------------------------
__global__ __launch_bounds__(256) void ball_query_kernel(
    const float* __restrict__ xyzw,      // [B][N][4]
    const float* __restrict__ new_xyz,   // [B][K][3]
    int* __restrict__ idx_buf,           // [BKK][S]
    int* __restrict__ scratch)           // [5][BKK][S] replica sink
{
    const int wave = threadIdx.x >> 6;
    const int lane = threadIdx.x & 63;
    const int qi   = blockIdx.x * 4 + wave;
    const int b    = qi >> 12;                   // K = 4096
    const int k    = qi & (KK - 1);

    const float R2 = (float)(0.4 * 0.4);

    const float* q = new_xyz + (size_t)(b * KK + k) * 3;
    const float qx = q[0], qy = q[1], qz = q[2];
    const float qq = __fadd_rn(__fadd_rn(__fmul_rn(qx, qx), __fmul_rn(qy, qy)),
                               __fmul_rn(qz, qz));

    const vfloat4* xw = (const vfloat4*)xyzw + (size_t)b * NN;
    int* outbase = (blockIdx.y == 0)
        ? idx_buf
        : scratch + (size_t)(blockIdx.y - 1) * BKK * SS;
    int* out = outbase + (size_t)qi * SS;

    int cnt = 0;
    int first = -1;

    auto process = [&](int base, vfloat4 v) {
        const float dot = __fadd_rn(__fadd_rn(__fmul_rn(qx, v.x), __fmul_rn(qy, v.y)),
                                    __fmul_rn(qz, v.z));
        const float d2 = __fsub_rn(__fadd_rn(qq, v.w), __fmul_rn(2.0f, dot));
        const bool inball = d2 < R2;
        const unsigned long long mask = __ballot(inball);
        if (mask) {
            if (first < 0) first = base + (int)__builtin_ctzll(mask);
            if (inball) {
                const int pos = cnt + __popcll(mask & ((1ull << lane) - 1ull));
                if (pos < SS) out[pos] = base + lane;
            }
            cnt += __popcll(mask);
        }
    };

    vfloat4 v0 = xw[lane];
    vfloat4 v1 = xw[64 + lane];
    vfloat4 v2 = xw[128 + lane];
    vfloat4 v3 = xw[192 + lane];

    for (int base = 0; base < NN; base += 256) {
        const int nb = (base + 256 < NN) ? base + 256 : 0;   // clamp; unused vals
        vfloat4 u0 = xw[nb + lane];
        vfloat4 u1 = xw[nb + 64 + lane];
        vfloat4 u2 = xw[nb + 128 + lane];
        vfloat4 u3 = xw[nb + 192 + lane];

        process(base, v0);
        process(base + 64, v1);
        process(base + 128, v2);
        process(base + 192, v3);
        if (cnt >= SS) break;

        v0 = u0; v1 = u1; v2 = u2; v3 = u3;
    }

    const int fill = (first < 0) ? 0 : first;
    if (lane < SS && lane >= cnt) out[lane] = fill;
}

// ---------------------------------------------------------------------------
// Kernel C: grouping. UNCHANGED single-copy form (G~7us gather + W~24us
// stores, 0 bank conflicts — validated round 10). Overwrites ALL of d_out,
// including the probe scratch region.
// ---------------------------------------------------------------------------
__global__ __launch_bounds__(256) void group_kernel(
    const float* __restrict__ xyzw,      // [B][N][4]
    const float* __restrict__ new_xyz,   // [B][K][3]
    const float* __restrict__ feat_t,    // [B][N][C]
    const int*   __restrict__ idx_buf,   // [B*K][S]
    float* __restrict__ out)             // [B][3][K][S] ++ [B][C][K][S]
{
    __shared__ float tile[SS * CC];      // 32 rows x 512B, linear, chunk-swizzled
    __shared__ float txyz[3][SS];

    const int t    = threadIdx.x;
    const int l    = t & 63;
    const int w    = t >> 6;             // wave 0..3
    const int bk   = blockIdx.x;
    const int b    = bk >> 12;
    const int k    = bk & (KK - 1);
    const int half = l >> 5;             // 0..1
    const int cl   = l & 31;             // chunk slot within row

#pragma unroll
    for (int p = 0; p < 4; ++p) {
        const int r = 8 * w + 2 * p;                 // wave-uniform row base
        const int s = r + half;
        const int n = idx_buf[bk * SS + s];
        const int chunk = cl ^ ((s >> 2) & 7);
        const float* src = feat_t + ((size_t)(b * NN + n)) * CC + 4 * chunk;
        __builtin_amdgcn_global_load_lds(
            (const __attribute__((address_space(1))) void*)src,
            (__attribute__((address_space(3))) void*)(tile + r * CC),
            16, 0, 0);
    }

    if (t < SS) {
        const int n = idx_buf[bk * SS + t];
        const float* q = new_xyz + (size_t)bk * 3;
        const vfloat4 wv = *((const vfloat4*)xyzw + (size_t)b * NN + n);
        txyz[0][t] = (wv.x - q[0]) / 0.4f;
        txyz[1][t] = (wv.y - q[1]) / 0.4f;
        txyz[2][t] = (wv.z - q[2]) / 0.4f;
    }

    __syncthreads();   // drains vmcnt(0): all DMAs + txyz visible

    float* out_xyz  = out;
    float* out_feat = out + (size_t)BB * 3 * KK * SS;

    const int sq = t & 7;
    const int c0 = t >> 3;               // 0..31
#pragma unroll
    for (int p = 0; p < 4; ++p) {
        const int c  = c0 + 32 * p;
        const int co = (((c >> 2) ^ sq) << 2) + (c & 3);   // un-swizzled col
        vfloat4 v;
        v.x = tile[(4 * sq + 0) * CC + co];
        v.y = tile[(4 * sq + 1) * CC + co];
        v.z = tile[(4 * sq + 2) * CC + co];
        v.w = tile[(4 * sq + 3) * CC + co];
        __builtin_nontemporal_store(
            v, (vfloat4*)(out_feat + (((size_t)(b * CC + c) * KK + k) * SS + 4 * sq)));
    }

    if (t < 24) {
        const int d   = t >> 3;
        const int sq2 = t & 7;
        const vfloat4 v = *(vfloat4*)&txyz[d][4 * sq2];
        __builtin_nontemporal_store(
            v, (vfloat4*)(out_xyz + (((size_t)(b * 3 + d) * KK + k) * SS + 4 * sq2)));
    }
}

extern "C" void kernel_launch(void* const* d_in, const int* in_sizes, int n_in,
                              void* d_out, int out_size, void* d_ws, size_t ws_size,
                              hipStream_t stream) {
    const float* xyz     = (const float*)d_in[0];   // [2][16384][3]
    const float* new_xyz = (const float*)d_in[1];   // [2][4096][3]
    const float* feat    = (const float*)d_in[2];   // [2][128][16384]
    float* out = (float*)d_out;

    // Workspace (17.5 MB): idx_buf 1MB | xyzw 0.5MB | feat_t 16MB
    int*   idx_buf = (int*)d_ws;
    float* xyzw    = (float*)((char*)d_ws + (1 << 20));
    float* feat_t  = (float*)((char*)d_ws + (1 << 20) + (512 << 10));

    // Probe scratch in d_out's feature region (group overwrites it after).
    int* scratch = (int*)(out + (size_t)BB * 3 * KK * SS);   // 5 x 1MB used

    transpose_prep_kernel<<<dim3(BB * (NN / 64)), dim3(256), 0, stream>>>(
        feat, xyz, feat_t, xyzw);

    // PROBE: grid.y = 6 replicas (5 sink + 1 writer). Revert next round.
    ball_query_kernel<<<dim3(BKK / 4, 6), dim3(256), 0, stream>>>(
        xyzw, new_xyz, idx_buf, scratch);

    group_kernel<<<dim3(BKK), dim3(256), 0, stream>>>(
        xyzw, new_xyz, feat_t, idx_buf, out);
}

// Round 14
// 87.543 us; speedup vs baseline: 2.9479x; 2.9479x over previous
//
#include <hip/hip_runtime.h>

#define BB 2
#define NN 16384
#define KK 4096
#define CC 128
#define SS 32
#define BKK (BB * KK)

typedef float vfloat4 __attribute__((ext_vector_type(4)));

// ---------------------------------------------------------------------------
// Kernel A: transpose features [B][C][N] -> [B][N][C] + fused xyzw prep.
// UNCHANGED (absmax 0.0 verified rounds 2-13).
// ---------------------------------------------------------------------------
__global__ __launch_bounds__(256) void transpose_prep_kernel(
    const float* __restrict__ feat, const float* __restrict__ xyz,
    float* __restrict__ feat_t, float* __restrict__ xyzw)
{
    __shared__ float tile[64][133];
    const int b  = blockIdx.x >> 8;          // NN/64 = 256 tiles per batch
    const int n0 = (blockIdx.x & 255) * 64;
    const int t  = threadIdx.x;

    if (t < 64) {
        const int i = b * NN + n0 + t;
        const float* p = xyz + (size_t)i * 3;
        const float x = p[0], y = p[1], z = p[2];
        const float pp = __fadd_rn(__fadd_rn(__fmul_rn(x, x), __fmul_rn(y, y)),
                                   __fmul_rn(z, z));
        vfloat4 v = {x, y, z, pp};
        *(vfloat4*)(xyzw + (size_t)i * 4) = v;
    }

    const int ln = t & 63;
    const int cr = t >> 6;                   // 0..3
#pragma unroll
    for (int p = 0; p < 32; ++p) {
        const int c = p * 4 + cr;
        tile[ln][c] = feat[((size_t)b * CC + c) * NN + n0 + ln];
    }
    __syncthreads();

    const int cl = t & 31;
    const int ns = t >> 5;                   // 0..7
#pragma unroll
    for (int p = 0; p < 8; ++p) {
        const int n = ns + 8 * p;
        float* dst = feat_t + ((size_t)(b * NN + n0 + n)) * CC;
#pragma unroll
        for (int j = 0; j < 4; ++j)
            dst[cl + 32 * j] = tile[n][cl + 32 * j];
    }
}

// ---------------------------------------------------------------------------
// Kernel S: query sort. Counting sort of the 8192 queries into 64 buckets by
// |q|^2 (scan length is ~monotone in it). Single block, LDS atomics, ~5us.
// qmap is a permutation; within-bucket order is atomic-nondeterministic but
// the OUTPUT is order-invariant (each query writes only its own idx row).
// Sort key uses plain fp math: affects grouping quality only, never values.
// ---------------------------------------------------------------------------
__global__ __launch_bounds__(1024) void qsort_kernel(
    const float* __restrict__ new_xyz,   // [B][K][3]
    int* __restrict__ qmap)              // [BKK]
{
    __shared__ int hist[64];
    __shared__ int base[64];
    __shared__ unsigned char bk[BKK];    // 8 KB

    const int t = threadIdx.x;
    if (t < 64) hist[t] = 0;
    __syncthreads();

#pragma unroll
    for (int c = 0; c < BKK / 1024; ++c) {
        const int q = c * 1024 + t;
        const float* p = new_xyz + (size_t)q * 3;
        const float qq = p[0] * p[0] + p[1] * p[1] + p[2] * p[2];
        int bkt = (int)(qq * 8.0f);
        bkt = bkt > 63 ? 63 : bkt;
        bk[q] = (unsigned char)bkt;
        atomicAdd(&hist[bkt], 1);
    }
    __syncthreads();

    if (t == 0) {
        int s = 0;
#pragma unroll
        for (int i = 0; i < 64; ++i) { base[i] = s; s += hist[i]; }
    }
    __syncthreads();

#pragma unroll
    for (int c = 0; c < BKK / 1024; ++c) {
        const int q = c * 1024 + t;
        const int pos = atomicAdd(&base[bk[q]], 1);
        qmap[pos] = q;
    }
}

// ---------------------------------------------------------------------------
// Kernel B: ball query — round-7 body VERBATIM (verified absmax 0.0), with
// one change: qi = qmap[slot], so the 4 waves of a block get sorted-adjacent
// queries with similar scan lengths. Round-13 probe showed block lifetime =
// max of 4 iid scan lengths (~54 chunks vs 26 mean, Occupancy 58%); sorting
// makes lifetime ~= own length.
// ---------------------------------------------------------------------------
__global__ __launch_bounds__(256) void ball_query_kernel(
    const float* __restrict__ xyzw,      // [B][N][4]
    const float* __restrict__ new_xyz,   // [B][K][3]
    const int* __restrict__ qmap,        // [BKK]
    int* __restrict__ idx_buf)           // [BKK][S]
{
    const int wave = threadIdx.x >> 6;
    const int lane = threadIdx.x & 63;
    const int qi   = qmap[blockIdx.x * 4 + wave];
    const int b    = qi >> 12;                   // K = 4096
    const int k    = qi & (KK - 1);

    const float R2 = (float)(0.4 * 0.4);

    const float* q = new_xyz + (size_t)(b * KK + k) * 3;
    const float qx = q[0], qy = q[1], qz = q[2];
    const float qq = __fadd_rn(__fadd_rn(__fmul_rn(qx, qx), __fmul_rn(qy, qy)),
                               __fmul_rn(qz, qz));

    const vfloat4* xw = (const vfloat4*)xyzw + (size_t)b * NN;
    int* out = idx_buf + (size_t)qi * SS;

    int cnt = 0;
    int first = -1;

    auto process = [&](int base, vfloat4 v) {
        const float dot = __fadd_rn(__fadd_rn(__fmul_rn(qx, v.x), __fmul_rn(qy, v.y)),
                                    __fmul_rn(qz, v.z));
        const float d2 = __fsub_rn(__fadd_rn(qq, v.w), __fmul_rn(2.0f, dot));
        const bool inball = d2 < R2;
        const unsigned long long mask = __ballot(inball);
        if (mask) {
            if (first < 0) first = base + (int)__builtin_ctzll(mask);
            if (inball) {
                const int pos = cnt + __popcll(mask & ((1ull << lane) - 1ull));
                if (pos < SS) out[pos] = base + lane;
            }
            cnt += __popcll(mask);
        }
    };

    vfloat4 v0 = xw[lane];
    vfloat4 v1 = xw[64 + lane];
    vfloat4 v2 = xw[128 + lane];
    vfloat4 v3 = xw[192 + lane];

    for (int base = 0; base < NN; base += 256) {
        const int nb = (base + 256 < NN) ? base + 256 : 0;   // clamp; unused vals
        vfloat4 u0 = xw[nb + lane];
        vfloat4 u1 = xw[nb + 64 + lane];
        vfloat4 u2 = xw[nb + 128 + lane];
        vfloat4 u3 = xw[nb + 192 + lane];

        process(base, v0);
        process(base + 64, v1);
        process(base + 128, v2);
        process(base + 192, v3);
        if (cnt >= SS) break;

        v0 = u0; v1 = u1; v2 = u2; v3 = u3;
    }

    const int fill = (first < 0) ? 0 : first;
    if (lane < SS && lane >= cnt) out[lane] = fill;
}

// ---------------------------------------------------------------------------
// Kernel C: grouping. UNCHANGED single-copy form (G~7us gather + W~24us
// stores, 0 bank conflicts — validated round 10).
// ---------------------------------------------------------------------------
__global__ __launch_bounds__(256) void group_kernel(
    const float* __restrict__ xyzw,      // [B][N][4]
    const float* __restrict__ new_xyz,   // [B][K][3]
    const float* __restrict__ feat_t,    // [B][N][C]
    const int*   __restrict__ idx_buf,   // [B*K][S]
    float* __restrict__ out)             // [B][3][K][S] ++ [B][C][K][S]
{
    __shared__ float tile[SS * CC];      // 32 rows x 512B, linear, chunk-swizzled
    __shared__ float txyz[3][SS];

    const int t    = threadIdx.x;
    const int l    = t & 63;
    const int w    = t >> 6;             // wave 0..3
    const int bk   = blockIdx.x;
    const int b    = bk >> 12;
    const int k    = bk & (KK - 1);
    const int half = l >> 5;             // 0..1
    const int cl   = l & 31;             // chunk slot within row

#pragma unroll
    for (int p = 0; p < 4; ++p) {
        const int r = 8 * w + 2 * p;                 // wave-uniform row base
        const int s = r + half;
        const int n = idx_buf[bk * SS + s];
        const int chunk = cl ^ ((s >> 2) & 7);
        const float* src = feat_t + ((size_t)(b * NN + n)) * CC + 4 * chunk;
        __builtin_amdgcn_global_load_lds(
            (const __attribute__((address_space(1))) void*)src,
            (__attribute__((address_space(3))) void*)(tile + r * CC),
            16, 0, 0);
    }

    if (t < SS) {
        const int n = idx_buf[bk * SS + t];
        const float* q = new_xyz + (size_t)bk * 3;
        const vfloat4 wv = *((const vfloat4*)xyzw + (size_t)b * NN + n);
        txyz[0][t] = (wv.x - q[0]) / 0.4f;
        txyz[1][t] = (wv.y - q[1]) / 0.4f;
        txyz[2][t] = (wv.z - q[2]) / 0.4f;
    }

    __syncthreads();   // drains vmcnt(0): all DMAs + txyz visible

    float* out_xyz  = out;
    float* out_feat = out + (size_t)BB * 3 * KK * SS;

    const int sq = t & 7;
    const int c0 = t >> 3;               // 0..31
#pragma unroll
    for (int p = 0; p < 4; ++p) {
        const int c  = c0 + 32 * p;
        const int co = (((c >> 2) ^ sq) << 2) + (c & 3);   // un-swizzled col
        vfloat4 v;
        v.x = tile[(4 * sq + 0) * CC + co];
        v.y = tile[(4 * sq + 1) * CC + co];
        v.z = tile[(4 * sq + 2) * CC + co];
        v.w = tile[(4 * sq + 3) * CC + co];
        __builtin_nontemporal_store(
            v, (vfloat4*)(out_feat + (((size_t)(b * CC + c) * KK + k) * SS + 4 * sq)));
    }

    if (t < 24) {
        const int d   = t >> 3;
        const int sq2 = t & 7;
        const vfloat4 v = *(vfloat4*)&txyz[d][4 * sq2];
        __builtin_nontemporal_store(
            v, (vfloat4*)(out_xyz + (((size_t)(b * 3 + d) * KK + k) * SS + 4 * sq2)));
    }
}

extern "C" void kernel_launch(void* const* d_in, const int* in_sizes, int n_in,
                              void* d_out, int out_size, void* d_ws, size_t ws_size,
                              hipStream_t stream) {
    const float* xyz     = (const float*)d_in[0];   // [2][16384][3]
    const float* new_xyz = (const float*)d_in[1];   // [2][4096][3]
    const float* feat    = (const float*)d_in[2];   // [2][128][16384]
    float* out = (float*)d_out;

    // Workspace: idx_buf 1MB | xyzw 0.5MB | feat_t 16MB | qmap 32KB
    int*   idx_buf = (int*)d_ws;
    float* xyzw    = (float*)((char*)d_ws + (1 << 20));
    float* feat_t  = (float*)((char*)d_ws + (1 << 20) + (512 << 10));
    int*   qmap    = (int*)((char*)d_ws + (1 << 20) + (512 << 10) + (CC * NN * BB) * 4);

    transpose_prep_kernel<<<dim3(BB * (NN / 64)), dim3(256), 0, stream>>>(
        feat, xyz, feat_t, xyzw);

    qsort_kernel<<<dim3(1), dim3(1024), 0, stream>>>(new_xyz, qmap);

    ball_query_kernel<<<dim3(BKK / 4), dim3(256), 0, stream>>>(
        xyzw, new_xyz, qmap, idx_buf);

    group_kernel<<<dim3(BKK), dim3(256), 0, stream>>>(
        xyzw, new_xyz, feat_t, idx_buf, out);
}